// Round 1
// baseline (185.526 us; speedup 1.0000x reference)
//
#include <hip/hip_runtime.h>
#include <math.h>

// x: (B, 63, 16) fp32, row stride 1008 floats; out: (B, 21) fp32.
// One wave (64 lanes) per row. Lane t<63 holds r[t]=x[row,t,0] in register.
// All stats via shuffle scans/reductions; no LDS.

__device__ __forceinline__ float wsum(float v) {
    #pragma unroll
    for (int d = 32; d > 0; d >>= 1) v += __shfl_xor(v, d, 64);
    return v;
}
__device__ __forceinline__ float wmax(float v) {
    #pragma unroll
    for (int d = 32; d > 0; d >>= 1) v = fmaxf(v, __shfl_xor(v, d, 64));
    return v;
}
__device__ __forceinline__ float wmin(float v) {
    #pragma unroll
    for (int d = 32; d > 0; d >>= 1) v = fminf(v, __shfl_xor(v, d, 64));
    return v;
}

__global__ __launch_bounds__(256) void regime_kernel(const float* __restrict__ x,
                                                     float* __restrict__ out,
                                                     int B) {
    const int wave = threadIdx.x >> 6;
    const int lane = threadIdx.x & 63;
    const int row  = blockIdx.x * 4 + wave;
    if (row >= B) return;

    const float* xr = x + (size_t)row * (63 * 16);

    // ---- loads ----
    float rt = 0.f, rsi62 = 0.f, vf = 0.f, momf62 = 0.f;
    if (lane < 63) {
        const float4 v = *(const float4*)(xr + lane * 16);  // channels 0..3 of step `lane`
        rt = v.x;                                            // r[lane]
        if (lane == 62) rsi62 = v.y;                         // rsi at last step
    }
    if (lane >= 42 && lane < 63) {
        const float4 v2 = *(const float4*)(xr + lane * 16 + 8);  // channels 8..11
        vf = v2.z;                                               // volf[lane]
    }
    if (lane == 62) momf62 = xr[62 * 16 + 15];                   // momf at last step

    const float r2 = rt * rt;

    // ---- inclusive prefix scans over lanes: r, r^2, |r|, r^3 (lanes>=63 contribute 0) ----
    float pr = rt, pq = r2, pa = fabsf(rt), pc = r2 * rt;
    #pragma unroll
    for (int d = 1; d < 64; d <<= 1) {
        float a = __shfl_up(pr, d, 64);
        float b = __shfl_up(pq, d, 64);
        float c = __shfl_up(pa, d, 64);
        float e = __shfl_up(pc, d, 64);
        if (lane >= d) { pr += a; pq += b; pa += c; pc += e; }
    }

    const float S  = __shfl(pr, 62, 64);  // sum r
    const float Q  = __shfl(pq, 62, 64);  // sum r^2
    const float SA = __shfl(pa, 62, 64);  // sum |r|
    const float SC = __shfl(pc, 62, 64);  // sum r^3

    const float mx = wmax(lane < 63 ? rt : -INFINITY);
    const float mn = wmin(lane < 63 ? rt :  INFINITY);

    // lag-1 product sum over t=0..61
    const float rnext = __shfl_down(rt, 1, 64);
    const float SL = wsum((lane < 62) ? rt * rnext : 0.f);

    // volf sum over steps 42..62 (vf already 0 elsewhere)
    const float SV = wsum(vf);

    // ---- vol_long (ddof=1, n=63) ----
    float varL = (Q - S * S / 63.f) / 62.f;
    const float vol_long = sqrtf(fmaxf(varL, 0.f));

    // ---- vol_short: window [42..62], n=21, ddof=1 ----
    const float P41r = __shfl(pr, 41, 64);
    const float P41q = __shfl(pq, 41, 64);
    const float Ss = S - P41r, Qs = Q - P41q;
    const float vol_short = sqrtf(fmaxf((Qs - Ss * Ss / 21.f) / 20.f, 0.f));

    // ---- 9 sliding windows j=62,57,...,22; window [j-21..j], n=22, ddof=1 ----
    const int k = (lane < 9) ? lane : 0;
    const int j = 62 - 5 * k;
    const float Wr = __shfl(pr, j, 64) - __shfl(pr, j - 22, 64);
    const float Wq = __shfl(pq, j, 64) - __shfl(pq, j - 22, 64);
    const float vsk = sqrtf(fmaxf((Wq - Wr * Wr / 22.f) / 21.f, 0.f));
    const float vsum = wsum(lane < 9 ? vsk : 0.f);
    const float vsqs = wsum(lane < 9 ? vsk * vsk : 0.f);
    const float vs0 = __shfl(vsk, 0, 64);
    const float vs8 = __shfl(vsk, 8, 64);
    const float vmean = vsum / 9.f;
    const float vol_persistence = sqrtf(fmaxf(vsqs / 9.f - vmean * vmean, 0.f));  // ddof=0
    const float vol_trend = vs0 - vs8;

    // ---- lag-1 autocorr over (r[0..61], r[1..62]) ----
    const float r0  = __shfl(rt, 0, 64);
    const float r62 = __shfl(rt, 62, 64);
    const float r42 = __shfl(rt, 42, 64);
    const float Sa = S - r62, Sb = S - r0;
    const float Qa = Q - r62 * r62, Qb = Q - r0 * r0;
    const float num = SL - Sa * Sb / 62.f;
    const float va = Qa - Sa * Sa / 62.f;
    const float vb = Qb - Sb * Sb / 62.f;
    const float corr = num / sqrtf(va * vb);
    const float trend = (corr != corr) ? 0.5f : fabsf(corr);  // NaN -> 0.5

    // ---- remaining scalars ----
    const float mean_returns = S / 63.f;
    const float abs_mean = SA / 63.f;
    const float range = mx - mn;
    float skew = 0.f;
    if (vol_long >= 1e-8f) {
        const float mu = mean_returns;
        const float cs = SC - 3.f * mu * Q + 2.f * 63.f * mu * mu * mu;  // sum (r-mu)^3
        skew = cs / (63.f * vol_long * vol_long * vol_long);
    }
    const float momentum_short = r62 / (r42 + 1e-8f) - 1.f;
    const float rsi_c  = __shfl(rsi62, 62, 64);
    const float momf_c = __shfl(momf62, 62, 64);
    const float vol_ratio = vol_short / (vol_long + 1e-8f);
    const float high_vol = (vol_short > 0.03f) ? 1.f : 0.f;
    const float med_vol  = (vol_short >= 0.01f && vol_short <= 0.03f) ? 1.f : 0.f;
    const float low_vol  = (vol_short < 0.01f) ? 1.f : 0.f;
    const float vol_feature_mean = SV / 21.f;

    // ---- write 21 features, lane f writes feature f ----
    if (lane < 21) {
        float f;
        switch (lane) {
            case 0:  f = high_vol; break;
            case 1:  f = med_vol; break;
            case 2:  f = low_vol; break;
            case 3:  f = trend; break;
            case 4:  f = vol_ratio; break;
            case 5:  f = mean_returns; break;
            case 6:  f = abs_mean; break;
            case 7:  f = range; break;
            case 8:  f = skew; break;
            case 9:  f = momentum_short; break;
            case 10: f = rsi_c; break;
            case 11: f = vol_feature_mean; break;
            case 12: f = momf_c; break;
            case 13: f = 0.f;   break;  // relative_return
            case 14: f = 1.f;   break;  // relative_vol
            case 15: f = 1.f;   break;  // beta
            case 16: f = 0.f;   break;  // relative_strength
            case 17: f = 0.02f; break;  // market_vol_level
            case 18: f = vol_persistence; break;
            case 19: f = vol_trend; break;
            default: f = 0.f;   break;  // regime_shift
        }
        out[(size_t)row * 21 + lane] = f;
    }
}

extern "C" void kernel_launch(void* const* d_in, const int* in_sizes, int n_in,
                              void* d_out, int out_size, void* d_ws, size_t ws_size,
                              hipStream_t stream) {
    const float* x = (const float*)d_in[0];
    float* out = (float*)d_out;
    const int B = in_sizes[0] / (63 * 16);
    const int blocks = (B + 3) / 4;  // 4 waves per block, one row per wave
    regime_kernel<<<blocks, 256, 0, stream>>>(x, out, B);
}